// Round 2
// baseline (64.487 us; speedup 1.0000x reference)
//
#include <hip/hip_runtime.h>
#include <math.h>

// Key observation: the reference's _volume_density sums jnp.ones over the K
// axis, so counts == MAX_K == 64 for EVERY point regardless of xyz. Hence
// dens is a constant, d_mean is that same constant for every batch, and the
// output is a tiny fixed-input MLP evaluated once. xyz never affects the
// output. One wave does everything.

#define MAX_K_F 64.0f

__global__ __launch_bounds__(64) void adaptive_threshold_mlp(
    const float* __restrict__ W1, const float* __restrict__ b1,
    const float* __restrict__ W2, const float* __restrict__ b2,
    const float* __restrict__ W3, const float* __restrict__ b3,
    float* __restrict__ out, int out_n)
{
    __shared__ float h1[64];
    const int j = threadIdx.x;  // 0..63, one wave

    // vol = 4/3 * 3.14159 * radius^3 (radius = 1.0); match reference arithmetic
    const float vol = (float)(4.0 / 3.0 * 3.14159);
    const float d_mean = MAX_K_F / vol;   // == dens == d_mean for every batch

    // Layer 1: (1 -> 64), W1 is (64,1): h1[j] = relu(d_mean * W1[j] + b1[j])
    h1[j] = fmaxf(fmaf(d_mean, W1[j], b1[j]), 0.0f);
    __syncthreads();

    // Layer 2: (64 -> 64): h2_j = relu(sum_k W2[j,k] * h1[k] + b2[j])
    float acc = b2[j];
    const float* w2row = W2 + j * 64;
    #pragma unroll 16
    for (int k = 0; k < 64; ++k) acc = fmaf(w2row[k], h1[k], acc);
    const float h2 = fmaxf(acc, 0.0f);

    // Layer 3: (64 -> 1) as a wave-wide dot product + shuffle reduction.
    float part = W3[j] * h2;
    #pragma unroll
    for (int off = 32; off > 0; off >>= 1)
        part += __shfl_down(part, off, 64);

    if (j == 0) {
        const float a = part + b3[0];
        const float t = 1.0f / (1.0f + expf(-a));
        const float thr = 20.0f + 40.0f * t;   // MIN_D + (MAX_D-MIN_D)*t
        for (int b = 0; b < out_n; ++b) out[b] = thr;  // same for all batches
    }
}

extern "C" void kernel_launch(void* const* d_in, const int* in_sizes, int n_in,
                              void* d_out, int out_size, void* d_ws, size_t ws_size,
                              hipStream_t stream) {
    // inputs: 0=xyz (unused by the math), 1=W1, 2=b1, 3=W2, 4=b2, 5=W3, 6=b3
    const float* W1 = (const float*)d_in[1];
    const float* b1 = (const float*)d_in[2];
    const float* W2 = (const float*)d_in[3];
    const float* b2 = (const float*)d_in[4];
    const float* W3 = (const float*)d_in[5];
    const float* b3 = (const float*)d_in[6];
    float* out = (float*)d_out;

    adaptive_threshold_mlp<<<1, 64, 0, stream>>>(W1, b1, W2, b2, W3, b3, out, out_size);
}